// Round 1
// baseline (9366.346 us; speedup 1.0000x reference)
//
#include <hip/hip_runtime.h>
#include <cstdint>
#include <cstddef>

// Problem constants
#define V_ 10000
#define E_ 512
#define H_ 1024
#define L_ 2
#define B_ 64
#define T_ 128
#define G4_ (4 * H_)   // 4096 gate width

// ---------------------------------------------------------------------------
// Embedding + concat: seq (T, B, E) rows m = t*64 + b
//   t==0 -> images[b], t>0 -> embed_table[captions[b][t-1]]
// ---------------------------------------------------------------------------
__global__ __launch_bounds__(128) void embed_kernel(
    const float* __restrict__ images, const int* __restrict__ captions,
    const float* __restrict__ table, float* __restrict__ seq)
{
    const int m = blockIdx.x;            // 0..8191, m = t*64 + b
    const int t = m >> 6, b = m & 63;
    const float* src;
    if (t == 0) src = images + (size_t)b * E_;
    else        src = table + (size_t)captions[b * T_ + (t - 1)] * E_;
    float4 v = ((const float4*)src)[threadIdx.x];
    ((float4*)(seq + (size_t)m * E_))[threadIdx.x] = v;
}

// ---------------------------------------------------------------------------
// f32 SGEMM, 128x128 tile, BK=8, 8x8 per thread, 256 threads.
//   C(M,N) = A(M,K) @ op(B) + bias1 + bias2
//   BNK=true : Bm is (N,K) row-major, computes A @ Bm^T
//   BNK=false: Bm is (K,N) row-major, computes A @ Bm
// All of M,N,K assumed multiples of the tile sizes (they are here).
// ---------------------------------------------------------------------------
template<bool BNK>
__global__ __launch_bounds__(256) void sgemm_kernel(
    const float* __restrict__ A, const float* __restrict__ Bm, float* __restrict__ C,
    int M, int N, int K,
    const float* __restrict__ bias1, const float* __restrict__ bias2)
{
    __shared__ float As[8][128];
    __shared__ float Bs[8][128];
    const int bm = blockIdx.y * 128, bn = blockIdx.x * 128;
    const int tid = threadIdx.x;
    const int tx = tid & 15, ty = tid >> 4;

    float acc[8][8] = {};

    for (int k0 = 0; k0 < K; k0 += 8) {
        {   // A tile: 128 rows x 8 k  (transpose into As[k][m])
            const int row = tid >> 1, kq = (tid & 1) * 4;
            float4 v = *(const float4*)&A[(size_t)(bm + row) * K + k0 + kq];
            As[kq + 0][row] = v.x; As[kq + 1][row] = v.y;
            As[kq + 2][row] = v.z; As[kq + 3][row] = v.w;
        }
        if (BNK) {
            const int row = tid >> 1, kq = (tid & 1) * 4;
            float4 v = *(const float4*)&Bm[(size_t)(bn + row) * K + k0 + kq];
            Bs[kq + 0][row] = v.x; Bs[kq + 1][row] = v.y;
            Bs[kq + 2][row] = v.z; Bs[kq + 3][row] = v.w;
        } else {
            const int kr = tid >> 5, c4 = (tid & 31) * 4;
            float4 v = *(const float4*)&Bm[(size_t)(k0 + kr) * N + bn + c4];
            *(float4*)&Bs[kr][c4] = v;
        }
        __syncthreads();
        #pragma unroll
        for (int k = 0; k < 8; ++k) {
            float a[8], b[8];
            *(float4*)&a[0] = *(const float4*)&As[k][ty * 8];
            *(float4*)&a[4] = *(const float4*)&As[k][ty * 8 + 4];
            *(float4*)&b[0] = *(const float4*)&Bs[k][tx * 8];
            *(float4*)&b[4] = *(const float4*)&Bs[k][tx * 8 + 4];
            #pragma unroll
            for (int i = 0; i < 8; ++i)
                #pragma unroll
                for (int j = 0; j < 8; ++j)
                    acc[i][j] += a[i] * b[j];
        }
        __syncthreads();
    }

    float bv[8];
    #pragma unroll
    for (int j = 0; j < 8; ++j) {
        float x = 0.f;
        if (bias1) x += bias1[bn + tx * 8 + j];
        if (bias2) x += bias2[bn + tx * 8 + j];
        bv[j] = x;
    }
    #pragma unroll
    for (int i = 0; i < 8; ++i) {
        float o[8];
        #pragma unroll
        for (int j = 0; j < 8; ++j) o[j] = acc[i][j] + bv[j];
        float* cp = &C[(size_t)(bm + ty * 8 + i) * N + bn + tx * 8];
        *(float4*)&cp[0] = *(float4*)&o[0];
        *(float4*)&cp[4] = *(float4*)&o[4];
    }
}

// ---------------------------------------------------------------------------
// One LSTM step (one layer):
//   gates(64,4096) = X[t] + u_prev(64,1024) @ Whhr^T        (Whhr = W_hh@W_hr)
//   c_new = sig(f)*c + sig(i)*tanh(g);  u = sig(o)*tanh(c_new)
// grid 256 blocks (4 h-columns each), 256 threads: thread = (b, hc).
// u staged in LDS [b][k] stride 129 (conflict-free scalar reads);
// W rows (16 per block) staged in LDS, read as broadcast float4.
// ---------------------------------------------------------------------------
#define US 129
#define WS 132
__global__ __launch_bounds__(256) void lstm_step_kernel(
    const float* __restrict__ X,      // (T*B, 4096), row = t*64+b (biases folded in)
    const float* __restrict__ Whhr,   // (4096, 1024)
    const float* __restrict__ Uprev,  // (64, 1024)
    float* __restrict__ Uout,         // (64, 1024)
    float* __restrict__ Cst,          // (64, 1024)
    int t)
{
    __shared__ float u_lds[64 * US];
    __shared__ float w_lds[16 * WS];
    const int tid = threadIdx.x;
    const int h0 = blockIdx.x * 4;
    const int b = tid & 63, hc = tid >> 6;

    float acc0 = 0.f, acc1 = 0.f, acc2 = 0.f, acc3 = 0.f;

    for (int kc = 0; kc < H_; kc += 128) {
        // stage u chunk: 64 rows x 128 = 2048 float4-quads worth (8 per thread)
        #pragma unroll
        for (int j = 0; j < 8; ++j) {
            int idx = j * 256 + tid;              // 0..2047
            int row = idx >> 5;                   // 0..63
            int c4  = (idx & 31) * 4;             // 0..124
            float4 v = *(const float4*)&Uprev[(size_t)row * H_ + kc + c4];
            u_lds[row * US + c4 + 0] = v.x;
            u_lds[row * US + c4 + 1] = v.y;
            u_lds[row * US + c4 + 2] = v.z;
            u_lds[row * US + c4 + 3] = v.w;
        }
        // stage W chunk: 16 rows (r = g*4 + hh -> Whhr row g*1024 + h0 + hh) x 128
        #pragma unroll
        for (int j = 0; j < 2; ++j) {
            int idx = j * 256 + tid;              // 0..511
            int r  = idx >> 5;                    // 0..15
            int c4 = (idx & 31) * 4;
            int g = r >> 2, hh = r & 3;
            float4 v = *(const float4*)&Whhr[(size_t)(g * H_ + h0 + hh) * H_ + kc + c4];
            *(float4*)&w_lds[r * WS + c4] = v;
        }
        __syncthreads();

        const float* ur = &u_lds[b * US];
        const float* wi = &w_lds[(0 * 4 + hc) * WS];
        const float* wf = &w_lds[(1 * 4 + hc) * WS];
        const float* wg = &w_lds[(2 * 4 + hc) * WS];
        const float* wo = &w_lds[(3 * 4 + hc) * WS];
        #pragma unroll 4
        for (int k = 0; k < 128; k += 4) {
            float u0 = ur[k], u1 = ur[k + 1], u2 = ur[k + 2], u3 = ur[k + 3];
            float4 vi = *(const float4*)&wi[k];
            float4 vf = *(const float4*)&wf[k];
            float4 vg = *(const float4*)&wg[k];
            float4 vo = *(const float4*)&wo[k];
            acc0 += u0 * vi.x + u1 * vi.y + u2 * vi.z + u3 * vi.w;
            acc1 += u0 * vf.x + u1 * vf.y + u2 * vf.z + u3 * vf.w;
            acc2 += u0 * vg.x + u1 * vg.y + u2 * vg.z + u3 * vg.w;
            acc3 += u0 * vo.x + u1 * vo.y + u2 * vo.z + u3 * vo.w;
        }
        __syncthreads();
    }

    const size_t xr = (size_t)(t * B_ + b) * G4_ + h0 + hc;
    float gi = acc0 + X[xr];
    float gf = acc1 + X[xr + H_];
    float gg = acc2 + X[xr + 2 * H_];
    float go = acc3 + X[xr + 3 * H_];

    const int ch = b * H_ + h0 + hc;
    float c_old = Cst[ch];
    float si = 1.f / (1.f + __expf(-gi));
    float sf = 1.f / (1.f + __expf(-gf));
    float so = 1.f / (1.f + __expf(-go));
    float tg = tanhf(gg);
    float cn = sf * c_old + si * tg;
    float un = so * tanhf(cn);
    Cst[ch]  = cn;
    Uout[ch] = un;
}

// ---------------------------------------------------------------------------
// Row softmax over E=512; input rows m = t*64+b, output row (b, t).
// One wave per row, 4 rows per block.
// ---------------------------------------------------------------------------
__global__ __launch_bounds__(256) void softmax_kernel(
    const float* __restrict__ LOG, float* __restrict__ out)
{
    const int lane = threadIdx.x & 63;
    const int r = blockIdx.x * 4 + (threadIdx.x >> 6);   // 0..8191
    const float* src = LOG + (size_t)r * E_;
    float v[8];
    *(float4*)&v[0] = ((const float4*)src)[lane * 2];
    *(float4*)&v[4] = ((const float4*)src)[lane * 2 + 1];

    float m = v[0];
    #pragma unroll
    for (int i = 1; i < 8; ++i) m = fmaxf(m, v[i]);
    #pragma unroll
    for (int off = 32; off > 0; off >>= 1) m = fmaxf(m, __shfl_xor(m, off, 64));

    float s = 0.f;
    #pragma unroll
    for (int i = 0; i < 8; ++i) { v[i] = expf(v[i] - m); s += v[i]; }
    #pragma unroll
    for (int off = 32; off > 0; off >>= 1) s += __shfl_xor(s, off, 64);
    const float inv = 1.f / s;

    const int t = r >> 6, b = r & 63;
    float* dst = out + ((size_t)b * T_ + t) * E_;
    #pragma unroll
    for (int i = 0; i < 8; ++i) v[i] *= inv;
    ((float4*)dst)[lane * 2]     = *(float4*)&v[0];
    ((float4*)dst)[lane * 2 + 1] = *(float4*)&v[4];
}

// ---------------------------------------------------------------------------
extern "C" void kernel_launch(void* const* d_in, const int* in_sizes, int n_in,
                              void* d_out, int out_size, void* d_ws, size_t ws_size,
                              hipStream_t stream)
{
    const float* images   = (const float*)d_in[0];   // (B,1,E)
    const int*   captions = (const int*)  d_in[1];   // (B,T)
    const float* table    = (const float*)d_in[2];   // (V,E)
    const float* W_ih     = (const float*)d_in[3];   // (L,4H,E)
    const float* W_hh     = (const float*)d_in[4];   // (L,4H,E)
    const float* W_hr     = (const float*)d_in[5];   // (L,E,H)
    const float* b_ih     = (const float*)d_in[6];   // (L,4H)
    const float* b_hh     = (const float*)d_in[7];   // (L,4H)
    float* out = (float*)d_out;                      // (B,T,E) f32

    // Workspace layout (floats)
    float* X    = (float*)d_ws;                  // 8192*4096     (later reused for logits)
    float* seq  = X    + (size_t)8192 * 4096;    // 8192*512      (later reused for H0)
    float* U    = seq  + (size_t)8192 * 512;     // 129*64*1024   (U[0] = zeros)
    float* Whhr = U    + (size_t)129 * 64 * 1024;// 4096*1024
    float* Cst  = Whhr + (size_t)4096 * 1024;    // 64*1024

    const size_t ustep = (size_t)B_ * H_;        // 65536 floats per step

    // 1. build sequence
    embed_kernel<<<T_ * B_, 128, 0, stream>>>(images, captions, table, seq);

    for (int l = 0; l < L_; ++l) {
        const float* wih = W_ih + (size_t)l * G4_ * E_;
        const float* whh = W_hh + (size_t)l * G4_ * E_;
        const float* whr = W_hr + (size_t)l * E_ * H_;
        const float* bih = b_ih + (size_t)l * G4_;
        const float* bhh = b_hh + (size_t)l * G4_;
        const float* inp = seq;                  // layer 0: seq, layer 1: H0 (same slot)

        // 2. Whhr = W_hh[l] (4096,512) @ W_hr[l] (512,1024)
        sgemm_kernel<false><<<dim3(H_ / 128, G4_ / 128), 256, 0, stream>>>(
            whh, whr, Whhr, G4_, H_, E_, nullptr, nullptr);

        // 3. X = inp (8192,512) @ W_ih[l]^T (4096,512) + b_ih + b_hh
        sgemm_kernel<true><<<dim3(G4_ / 128, (T_ * B_) / 128), 256, 0, stream>>>(
            inp, wih, X, T_ * B_, G4_, E_, bih, bhh);

        // 4. zero initial u and c
        hipMemsetAsync(U,   0, ustep * sizeof(float), stream);
        hipMemsetAsync(Cst, 0, ustep * sizeof(float), stream);

        // 5. recurrence
        for (int t = 0; t < T_; ++t) {
            lstm_step_kernel<<<256, 256, 0, stream>>>(
                X, Whhr, U + (size_t)t * ustep, U + (size_t)(t + 1) * ustep, Cst, t);
        }

        // 6. project all h: (8192,1024) @ W_hr[l]^T (512,1024)
        //    layer 0 -> H0 (seq slot), layer 1 -> logits (X slot)
        float* proj_dst = (l == 0) ? seq : X;
        sgemm_kernel<true><<<dim3(E_ / 128, (T_ * B_) / 128), 256, 0, stream>>>(
            U + ustep, whr, proj_dst, T_ * B_, E_, H_, nullptr, nullptr);
    }

    // 7. softmax over E, reorder (t,b) -> (b,t)
    softmax_kernel<<<(T_ * B_) / 4, 256, 0, stream>>>(X, out);

    (void)in_sizes; (void)n_in; (void)out_size; (void)ws_size;
}

// Round 2
// 8920.962 us; speedup vs baseline: 1.0499x; 1.0499x over previous
//
#include <hip/hip_runtime.h>
#include <cstdint>
#include <cstddef>

// Problem constants
#define V_ 10000
#define E_ 512
#define H_ 1024
#define L_ 2
#define B_ 64
#define T_ 128
#define G4_ (4 * H_)   // 4096 gate width

typedef __attribute__((ext_vector_type(8))) short bf16x8;
typedef __attribute__((ext_vector_type(4))) float f32x4;

// ---------------------------------------------------------------------------
// bf16 split helpers (RNE, hand-rolled: no NaN/inf in this problem)
// a = b2f(h) + b2f(l) + b2f(q) + O(2^-27 |a|)
// ---------------------------------------------------------------------------
__device__ __forceinline__ unsigned short f2b(float x) {
    unsigned u = __float_as_uint(x);
    unsigned r = (u + 0x7FFFu + ((u >> 16) & 1u)) >> 16;
    return (unsigned short)r;
}
__device__ __forceinline__ float b2f(unsigned short h) {
    return __uint_as_float(((unsigned)h) << 16);
}
__device__ __forceinline__ void split3(float a, unsigned short& h, unsigned short& l, unsigned short& q) {
    h = f2b(a); float r = a - b2f(h);     // exact (Sterbenz)
    l = f2b(r); float r2 = r - b2f(l);
    q = f2b(r2);
}

// ---------------------------------------------------------------------------
// Embedding + concat: seq (T, B, E) rows m = t*64 + b
// ---------------------------------------------------------------------------
__global__ __launch_bounds__(128) void embed_kernel(
    const float* __restrict__ images, const int* __restrict__ captions,
    const float* __restrict__ table, float* __restrict__ seq)
{
    const int m = blockIdx.x;            // 0..8191, m = t*64 + b
    const int t = m >> 6, b = m & 63;
    const float* src;
    if (t == 0) src = images + (size_t)b * E_;
    else        src = table + (size_t)captions[b * T_ + (t - 1)] * E_;
    float4 v = ((const float4*)src)[threadIdx.x];
    ((float4*)(seq + (size_t)m * E_))[threadIdx.x] = v;
}

// ---------------------------------------------------------------------------
// Split-bf16x6 MFMA GEMM.  C(M,N) = A(M,K) @ op(B) [+ bias1 + bias2]
//   A row-major (M,K) f32.
//   BNK=true : Bm is (N,K) row-major -> A @ Bm^T
//   BNK=false: Bm is (K,N) row-major -> A @ Bm
// Each operand split in-kernel into 3 bf16 planes (hi/lo/q); 6 MFMA products
// (hh, hl, lh, ll, hq, qh) accumulate into one f32 acc => ~f32 accuracy.
// Tile 128x128, BK=32, 4 waves, each wave 64x64 via 4x4 16x16x32 frags.
// M,N multiples of 128; K multiple of 32.
// ---------------------------------------------------------------------------
template<bool BNK>
__global__ __launch_bounds__(256) void mfma_gemm(
    const float* __restrict__ A, const float* __restrict__ Bm, float* __restrict__ C,
    int M, int N, int K,
    const float* __restrict__ bias1, const float* __restrict__ bias2)
{
    __shared__ unsigned short As[3][128][40];   // pad 32->40: 16B-aligned rows
    __shared__ unsigned short Bs[3][128][40];
    const int bm = blockIdx.y * 128, bn = blockIdx.x * 128;
    const int tid = threadIdx.x;
    const int lane = tid & 63, wid = tid >> 6;
    const int wm = wid >> 1, wn = wid & 1;      // wave -> 64x64 quadrant
    const int lr = lane & 15, lk = (lane >> 4) * 8;

    f32x4 acc[4][4] = {};

    for (int k0 = 0; k0 < K; k0 += 32) {
        // ---- stage A tile (128 rows x 32 k), split into 3 bf16 planes ----
        #pragma unroll
        for (int p = 0; p < 4; ++p) {
            int flat = p * 256 + tid;
            int c4 = flat & 7, r = flat >> 3;
            float4 v = *(const float4*)&A[(size_t)(bm + r) * K + k0 + c4 * 4];
            unsigned short h[4], l[4], q[4];
            split3(v.x, h[0], l[0], q[0]); split3(v.y, h[1], l[1], q[1]);
            split3(v.z, h[2], l[2], q[2]); split3(v.w, h[3], l[3], q[3]);
            unsigned* dh = (unsigned*)&As[0][r][c4 * 4];
            dh[0] = h[0] | ((unsigned)h[1] << 16); dh[1] = h[2] | ((unsigned)h[3] << 16);
            unsigned* dl = (unsigned*)&As[1][r][c4 * 4];
            dl[0] = l[0] | ((unsigned)l[1] << 16); dl[1] = l[2] | ((unsigned)l[3] << 16);
            unsigned* dq = (unsigned*)&As[2][r][c4 * 4];
            dq[0] = q[0] | ((unsigned)q[1] << 16); dq[1] = q[2] | ((unsigned)q[3] << 16);
        }
        // ---- stage B tile as [n][k] bf16 planes ----
        if (BNK) {
            #pragma unroll
            for (int p = 0; p < 4; ++p) {
                int flat = p * 256 + tid;
                int c4 = flat & 7, r = flat >> 3;
                float4 v = *(const float4*)&Bm[(size_t)(bn + r) * K + k0 + c4 * 4];
                unsigned short h[4], l[4], q[4];
                split3(v.x, h[0], l[0], q[0]); split3(v.y, h[1], l[1], q[1]);
                split3(v.z, h[2], l[2], q[2]); split3(v.w, h[3], l[3], q[3]);
                unsigned* dh = (unsigned*)&Bs[0][r][c4 * 4];
                dh[0] = h[0] | ((unsigned)h[1] << 16); dh[1] = h[2] | ((unsigned)h[3] << 16);
                unsigned* dl = (unsigned*)&Bs[1][r][c4 * 4];
                dl[0] = l[0] | ((unsigned)l[1] << 16); dl[1] = l[2] | ((unsigned)l[3] << 16);
                unsigned* dq = (unsigned*)&Bs[2][r][c4 * 4];
                dq[0] = q[0] | ((unsigned)q[1] << 16); dq[1] = q[2] | ((unsigned)q[3] << 16);
            }
        } else {
            #pragma unroll
            for (int p = 0; p < 4; ++p) {
                int flat = p * 256 + tid;
                int n4 = flat & 31, kr = flat >> 5;
                float4 v = *(const float4*)&Bm[(size_t)(k0 + kr) * N + bn + n4 * 4];
                float vv[4] = {v.x, v.y, v.z, v.w};
                #pragma unroll
                for (int j = 0; j < 4; ++j) {
                    unsigned short h, l, q; split3(vv[j], h, l, q);
                    Bs[0][n4 * 4 + j][kr] = h;
                    Bs[1][n4 * 4 + j][kr] = l;
                    Bs[2][n4 * 4 + j][kr] = q;
                }
            }
        }
        __syncthreads();

        bf16x8 af[3][4], bf[3][4];
        #pragma unroll
        for (int pl = 0; pl < 3; ++pl)
            #pragma unroll
            for (int m = 0; m < 4; ++m) {
                af[pl][m] = *(const bf16x8*)&As[pl][wm * 64 + m * 16 + lr][lk];
                bf[pl][m] = *(const bf16x8*)&Bs[pl][wn * 64 + m * 16 + lr][lk];
            }
        #pragma unroll
        for (int m = 0; m < 4; ++m)
            #pragma unroll
            for (int n = 0; n < 4; ++n) {
                acc[m][n] = __builtin_amdgcn_mfma_f32_16x16x32_bf16(af[0][m], bf[0][n], acc[m][n], 0, 0, 0);
                acc[m][n] = __builtin_amdgcn_mfma_f32_16x16x32_bf16(af[0][m], bf[1][n], acc[m][n], 0, 0, 0);
                acc[m][n] = __builtin_amdgcn_mfma_f32_16x16x32_bf16(af[1][m], bf[0][n], acc[m][n], 0, 0, 0);
                acc[m][n] = __builtin_amdgcn_mfma_f32_16x16x32_bf16(af[1][m], bf[1][n], acc[m][n], 0, 0, 0);
                acc[m][n] = __builtin_amdgcn_mfma_f32_16x16x32_bf16(af[0][m], bf[2][n], acc[m][n], 0, 0, 0);
                acc[m][n] = __builtin_amdgcn_mfma_f32_16x16x32_bf16(af[2][m], bf[0][n], acc[m][n], 0, 0, 0);
            }
        __syncthreads();
    }

    // ---- epilogue: C/D frag layout col = lane&15, row = (lane>>4)*4 + r ----
    float bv[4];
    #pragma unroll
    for (int n = 0; n < 4; ++n) {
        int col = bn + wn * 64 + n * 16 + lr;
        float x = 0.f;
        if (bias1) x += bias1[col];
        if (bias2) x += bias2[col];
        bv[n] = x;
    }
    #pragma unroll
    for (int m = 0; m < 4; ++m) {
        int rbase = bm + wm * 64 + m * 16 + (lane >> 4) * 4;
        #pragma unroll
        for (int n = 0; n < 4; ++n) {
            int col = bn + wn * 64 + n * 16 + lr;
            #pragma unroll
            for (int r = 0; r < 4; ++r)
                C[(size_t)(rbase + r) * N + col] = acc[m][n][r] + bv[n];
        }
    }
}

// ---------------------------------------------------------------------------
// One LSTM step (unchanged from R1; R3 target)
// ---------------------------------------------------------------------------
#define US 129
#define WS 132
__global__ __launch_bounds__(256) void lstm_step_kernel(
    const float* __restrict__ X,      // (T*B, 4096), row = t*64+b (biases folded in)
    const float* __restrict__ Whhr,   // (4096, 1024)
    const float* __restrict__ Uprev,  // (64, 1024)
    float* __restrict__ Uout,         // (64, 1024)
    float* __restrict__ Cst,          // (64, 1024)
    int t)
{
    __shared__ float u_lds[64 * US];
    __shared__ float w_lds[16 * WS];
    const int tid = threadIdx.x;
    const int h0 = blockIdx.x * 4;
    const int b = tid & 63, hc = tid >> 6;

    float acc0 = 0.f, acc1 = 0.f, acc2 = 0.f, acc3 = 0.f;

    for (int kc = 0; kc < H_; kc += 128) {
        #pragma unroll
        for (int j = 0; j < 8; ++j) {
            int idx = j * 256 + tid;
            int row = idx >> 5;
            int c4  = (idx & 31) * 4;
            float4 v = *(const float4*)&Uprev[(size_t)row * H_ + kc + c4];
            u_lds[row * US + c4 + 0] = v.x;
            u_lds[row * US + c4 + 1] = v.y;
            u_lds[row * US + c4 + 2] = v.z;
            u_lds[row * US + c4 + 3] = v.w;
        }
        #pragma unroll
        for (int j = 0; j < 2; ++j) {
            int idx = j * 256 + tid;
            int r  = idx >> 5;
            int c4 = (idx & 31) * 4;
            int g = r >> 2, hh = r & 3;
            float4 v = *(const float4*)&Whhr[(size_t)(g * H_ + h0 + hh) * H_ + kc + c4];
            *(float4*)&w_lds[r * WS + c4] = v;
        }
        __syncthreads();

        const float* ur = &u_lds[b * US];
        const float* wi = &w_lds[(0 * 4 + hc) * WS];
        const float* wf = &w_lds[(1 * 4 + hc) * WS];
        const float* wg = &w_lds[(2 * 4 + hc) * WS];
        const float* wo = &w_lds[(3 * 4 + hc) * WS];
        #pragma unroll 4
        for (int k = 0; k < 128; k += 4) {
            float u0 = ur[k], u1 = ur[k + 1], u2 = ur[k + 2], u3 = ur[k + 3];
            float4 vi = *(const float4*)&wi[k];
            float4 vf = *(const float4*)&wf[k];
            float4 vg = *(const float4*)&wg[k];
            float4 vo = *(const float4*)&wo[k];
            acc0 += u0 * vi.x + u1 * vi.y + u2 * vi.z + u3 * vi.w;
            acc1 += u0 * vf.x + u1 * vf.y + u2 * vf.z + u3 * vf.w;
            acc2 += u0 * vg.x + u1 * vg.y + u2 * vg.z + u3 * vg.w;
            acc3 += u0 * vo.x + u1 * vo.y + u2 * vo.z + u3 * vo.w;
        }
        __syncthreads();
    }

    const size_t xr = (size_t)(t * B_ + b) * G4_ + h0 + hc;
    float gi = acc0 + X[xr];
    float gf = acc1 + X[xr + H_];
    float gg = acc2 + X[xr + 2 * H_];
    float go = acc3 + X[xr + 3 * H_];

    const int ch = b * H_ + h0 + hc;
    float c_old = Cst[ch];
    float si = 1.f / (1.f + __expf(-gi));
    float sf = 1.f / (1.f + __expf(-gf));
    float so = 1.f / (1.f + __expf(-go));
    float tg = tanhf(gg);
    float cn = sf * c_old + si * tg;
    float un = so * tanhf(cn);
    Cst[ch]  = cn;
    Uout[ch] = un;
}

// ---------------------------------------------------------------------------
// Row softmax over E=512; input rows m = t*64+b, output row (b, t).
// ---------------------------------------------------------------------------
__global__ __launch_bounds__(256) void softmax_kernel(
    const float* __restrict__ LOG, float* __restrict__ out)
{
    const int lane = threadIdx.x & 63;
    const int r = blockIdx.x * 4 + (threadIdx.x >> 6);
    const float* src = LOG + (size_t)r * E_;
    float v[8];
    *(float4*)&v[0] = ((const float4*)src)[lane * 2];
    *(float4*)&v[4] = ((const float4*)src)[lane * 2 + 1];

    float m = v[0];
    #pragma unroll
    for (int i = 1; i < 8; ++i) m = fmaxf(m, v[i]);
    #pragma unroll
    for (int off = 32; off > 0; off >>= 1) m = fmaxf(m, __shfl_xor(m, off, 64));

    float s = 0.f;
    #pragma unroll
    for (int i = 0; i < 8; ++i) { v[i] = expf(v[i] - m); s += v[i]; }
    #pragma unroll
    for (int off = 32; off > 0; off >>= 1) s += __shfl_xor(s, off, 64);
    const float inv = 1.f / s;

    const int t = r >> 6, b = r & 63;
    float* dst = out + ((size_t)b * T_ + t) * E_;
    #pragma unroll
    for (int i = 0; i < 8; ++i) v[i] *= inv;
    ((float4*)dst)[lane * 2]     = *(float4*)&v[0];
    ((float4*)dst)[lane * 2 + 1] = *(float4*)&v[4];
}

// ---------------------------------------------------------------------------
extern "C" void kernel_launch(void* const* d_in, const int* in_sizes, int n_in,
                              void* d_out, int out_size, void* d_ws, size_t ws_size,
                              hipStream_t stream)
{
    const float* images   = (const float*)d_in[0];   // (B,1,E)
    const int*   captions = (const int*)  d_in[1];   // (B,T)
    const float* table    = (const float*)d_in[2];   // (V,E)
    const float* W_ih     = (const float*)d_in[3];   // (L,4H,E)
    const float* W_hh     = (const float*)d_in[4];   // (L,4H,E)
    const float* W_hr     = (const float*)d_in[5];   // (L,E,H)
    const float* b_ih     = (const float*)d_in[6];   // (L,4H)
    const float* b_hh     = (const float*)d_in[7];   // (L,4H)
    float* out = (float*)d_out;                      // (B,T,E) f32

    // Workspace layout (floats) — identical to R1
    float* X    = (float*)d_ws;                  // 8192*4096     (later logits)
    float* seq  = X    + (size_t)8192 * 4096;    // 8192*512      (later H0)
    float* U    = seq  + (size_t)8192 * 512;     // 129*64*1024   (U[0] = zeros)
    float* Whhr = U    + (size_t)129 * 64 * 1024;// 4096*1024
    float* Cst  = Whhr + (size_t)4096 * 1024;    // 64*1024

    const size_t ustep = (size_t)B_ * H_;

    embed_kernel<<<T_ * B_, 128, 0, stream>>>(images, captions, table, seq);

    for (int l = 0; l < L_; ++l) {
        const float* wih = W_ih + (size_t)l * G4_ * E_;
        const float* whh = W_hh + (size_t)l * G4_ * E_;
        const float* whr = W_hr + (size_t)l * E_ * H_;
        const float* bih = b_ih + (size_t)l * G4_;
        const float* bhh = b_hh + (size_t)l * G4_;
        const float* inp = seq;

        // Whhr = W_hh[l] (4096,512) @ W_hr[l] (512,1024)
        mfma_gemm<false><<<dim3(H_ / 128, G4_ / 128), 256, 0, stream>>>(
            whh, whr, Whhr, G4_, H_, E_, nullptr, nullptr);

        // X = inp (8192,512) @ W_ih[l]^T + b_ih + b_hh
        mfma_gemm<true><<<dim3(G4_ / 128, (T_ * B_) / 128), 256, 0, stream>>>(
            inp, wih, X, T_ * B_, G4_, E_, bih, bhh);

        hipMemsetAsync(U,   0, ustep * sizeof(float), stream);
        hipMemsetAsync(Cst, 0, ustep * sizeof(float), stream);

        for (int t = 0; t < T_; ++t) {
            lstm_step_kernel<<<256, 256, 0, stream>>>(
                X, Whhr, U + (size_t)t * ustep, U + (size_t)(t + 1) * ustep, Cst, t);
        }

        // project all u: (8192,1024) @ W_hr[l]^T (512,1024 as N,K)
        float* proj_dst = (l == 0) ? seq : X;
        mfma_gemm<true><<<dim3(E_ / 128, (T_ * B_) / 128), 256, 0, stream>>>(
            U + ustep, whr, proj_dst, T_ * B_, E_, H_, nullptr, nullptr);
    }

    softmax_kernel<<<(T_ * B_) / 4, 256, 0, stream>>>(X, out);

    (void)in_sizes; (void)n_in; (void)out_size; (void)ws_size;
}